// Round 1
// baseline (267.399 us; speedup 1.0000x reference)
//
#include <hip/hip_runtime.h>

typedef __bf16 bf16x8 __attribute__((ext_vector_type(8)));
typedef float  f32x4  __attribute__((ext_vector_type(4)));
typedef unsigned short u16;
typedef unsigned int   u32;

#define MFMA(a,b,c) __builtin_amdgcn_mfma_f32_16x16x32_bf16((a),(b),(c),0,0,0)

__device__ __forceinline__ u16 f2bf(float f){
    u32 u = __builtin_bit_cast(u32, f);
    u += 0x7FFFu + ((u >> 16) & 1u);   // RNE
    return (u16)(u >> 16);
}

typedef __attribute__((address_space(3))) u32 lds32_t;
typedef __attribute__((address_space(1))) u32 glb32_t;

__device__ __forceinline__ void gll16(const u16* g, u16* l){
    __builtin_amdgcn_global_load_lds((const glb32_t*)g, (lds32_t*)l, 16, 0, 0);
}

// ---------------- convert kernels ----------------
__global__ __launch_bounds__(256) void cvt_x_kernel(const float* __restrict__ in,
                                                    u16* __restrict__ out, int n8){
    int i = blockIdx.x * 256 + threadIdx.x;
    if (i >= n8) return;
    const float4* p = (const float4*)in + (size_t)i * 2;
    float4 a = p[0], b = p[1];
    u16 r[8] = { f2bf(a.x), f2bf(a.y), f2bf(a.z), f2bf(a.w),
                 f2bf(b.x), f2bf(b.y), f2bf(b.z), f2bf(b.w) };
    *((uint4*)out + i) = *(const uint4*)r;
}

// in[R][C] fp32 -> out[C][R] bf16
__global__ __launch_bounds__(256) void tcvt_kernel(const float* __restrict__ in,
                                                   u16* __restrict__ out, int R, int C){
    __shared__ float tile[32][33];
    int c0 = blockIdx.x * 32, r0 = blockIdx.y * 32;
    int tx = threadIdx.x & 31, ty = threadIdx.x >> 5;   // ty 0..7
    #pragma unroll
    for (int i = 0; i < 32; i += 8)
        tile[ty + i][tx] = in[(size_t)(r0 + ty + i) * C + c0 + tx];
    __syncthreads();
    #pragma unroll
    for (int i = 0; i < 32; i += 8)
        out[(size_t)(c0 + ty + i) * R + r0 + tx] = f2bf(tile[tx][ty + i]);
}

// ---------------- shared GEMM mainloop: C[128][128] = A[128rows][512] * Bt[128rows][512]^T
// A,Bt row-major bf16, row stride 512 elems. LDS tiles XOR-preswizzled at stage, XOR-read.
__device__ __forceinline__ void gemm_core(const u16* __restrict__ A, const u16* __restrict__ Bt,
                                          int brow, int bcol, u16* ldsA, u16* ldsB,
                                          f32x4 acc[4][4]){
    const int t = threadIdx.x;
    const int lane = t & 63, wave = t >> 6;
    const int l16 = lane & 15, lg = lane >> 4;
    const int wrow = (wave & 1) << 6, wcol = (wave >> 1) << 6;

    for (int ks = 0; ks < 8; ++ks){
        if (ks) __syncthreads();
        #pragma unroll
        for (int iss = 0; iss < 4; ++iss){
            int chunk = iss * 256 + t;
            int row = chunk >> 3, c = chunk & 7;
            int sw = (c ^ (row & 7)) << 3;
            gll16(A  + (size_t)(brow + row) * 512 + ks * 64 + sw,
                  ldsA + (size_t)(iss * 256 + wave * 64) * 8);
            gll16(Bt + (size_t)(bcol + row) * 512 + ks * 64 + sw,
                  ldsB + (size_t)(iss * 256 + wave * 64) * 8);
        }
        __syncthreads();
        #pragma unroll
        for (int kc = 0; kc < 2; ++kc){
            bf16x8 af[4], bfr[4];
            #pragma unroll
            for (int m = 0; m < 4; ++m){
                int r = wrow + 16 * m + l16;
                af[m] = *(const bf16x8*)(ldsA + r * 64 + (((kc * 4 + lg) ^ (l16 & 7)) << 3));
            }
            #pragma unroll
            for (int n = 0; n < 4; ++n){
                int r = wcol + 16 * n + l16;
                bfr[n] = *(const bf16x8*)(ldsB + r * 64 + (((kc * 4 + lg) ^ (l16 & 7)) << 3));
            }
            #pragma unroll
            for (int m = 0; m < 4; ++m)
                #pragma unroll
                for (int n = 0; n < 4; ++n)
                    acc[m][n] = MFMA(af[m], bfr[n], acc[m][n]);
        }
    }
}

// ---------------- GEMM1: qkv, scatters q/k row-major per head, v transposed ----------------
__global__ __launch_bounds__(256) void gemm_qkv_kernel(const u16* __restrict__ A, const u16* __restrict__ Bt,
                                                       u16* __restrict__ qws, u16* __restrict__ kws,
                                                       u16* __restrict__ vtws){
    __shared__ u16 ldsA[128 * 64];
    __shared__ u16 ldsB[128 * 64];
    const f32x4 vzero = {0.f, 0.f, 0.f, 0.f};
    f32x4 acc[4][4];
    #pragma unroll
    for (int m = 0; m < 4; ++m)
        #pragma unroll
        for (int n = 0; n < 4; ++n) acc[m][n] = vzero;

    int brow = blockIdx.x * 128, bcol = blockIdx.y * 128;
    gemm_core(A, Bt, brow, bcol, ldsA, ldsB, acc);

    const int t = threadIdx.x, lane = t & 63, wave = t >> 6;
    const int l16 = lane & 15, lg = lane >> 4;
    const int wrow = (wave & 1) << 6, wcol = (wave >> 1) << 6;
    const int s = bcol >> 9;            // 0:q 1:k 2:v (uniform per block)

    if (s < 2){
        u16* dst = (s == 0) ? qws : kws;
        #pragma unroll
        for (int n = 0; n < 4; ++n){
            int e = (bcol & 511) + wcol + 16 * n + l16;
            int h = e >> 6, d = e & 63;
            #pragma unroll
            for (int m = 0; m < 4; ++m)
                #pragma unroll
                for (int r = 0; r < 4; ++r){
                    int mg = brow + wrow + 16 * m + 4 * lg + r;
                    int b = mg >> 12, nn = mg & 4095;
                    dst[(((size_t)(b * 8 + h) * 4096 + nn) << 6) + d] = f2bf(acc[m][n][r]);
                }
        }
    } else {
        #pragma unroll
        for (int n = 0; n < 4; ++n){
            int e = (bcol & 511) + wcol + 16 * n + l16;
            int h = e >> 6, d = e & 63;
            #pragma unroll
            for (int m = 0; m < 4; ++m)
                #pragma unroll
                for (int r = 0; r < 4; ++r){
                    int mg = brow + wrow + 16 * m + 4 * lg + r;
                    int b = mg >> 12, nn = mg & 4095;
                    vtws[((size_t)((b * 8 + h) * 64 + d) << 12) + nn] = f2bf(acc[m][n][r]);
                }
        }
    }
}

// ---------------- flash attention with diagonal mask ----------------
__global__ __launch_bounds__(256) void attn_kernel(const u16* __restrict__ q, const u16* __restrict__ k,
                                                   const u16* __restrict__ vt, u16* __restrict__ aout,
                                                   const float* __restrict__ temp){
    __shared__ u16 Kl[64 * 64];          // [kv][64] swizzled
    __shared__ u16 Vl[64 * 64];          // [d][kv] swizzled
    __shared__ u16 Pl[4][16 * 72];       // per-wave P tile, padded rows
    const int bid = blockIdx.x;
    const int qt = bid & 63, bh = bid >> 6;
    const int t = threadIdx.x, lane = t & 63, wave = t >> 6;
    const int l16 = lane & 15, lg = lane >> 4;
    const float scale = __expf(temp[0]);

    const int qrow = qt * 64 + wave * 16 + l16;
    const u16* qb = q + (((size_t)bh * 4096 + qrow) << 6);
    bf16x8 qa[2];
    qa[0] = *(const bf16x8*)(qb + (lg << 3));
    qa[1] = *(const bf16x8*)(qb + 32 + (lg << 3));

    const f32x4 vzero = {0.f, 0.f, 0.f, 0.f};
    f32x4 o[4];
    float mv[4], ls[4];
    #pragma unroll
    for (int i = 0; i < 4; ++i){ o[i] = vzero; mv[i] = -INFINITY; ls[i] = 0.f; }
    const int qg0 = qt * 64 + wave * 16 + lg * 4;

    for (int kb = 0; kb < 4096; kb += 64){
        __syncthreads();
        #pragma unroll
        for (int iss = 0; iss < 2; ++iss){
            int chunk = iss * 256 + t;
            int row = chunk >> 3, c = chunk & 7;
            int sw = (c ^ (row & 7)) << 3;
            gll16(k  + (((size_t)bh * 4096 + kb + row) << 6) + sw,
                  Kl + (iss * 256 + wave * 64) * 8);
            gll16(vt + ((size_t)(bh * 64 + row) << 12) + kb + sw,
                  Vl + (iss * 256 + wave * 64) * 8);
        }
        __syncthreads();

        // S = Q K^T
        f32x4 s[4];
        #pragma unroll
        for (int fc = 0; fc < 4; ++fc){
            s[fc] = vzero;
            #pragma unroll
            for (int dc = 0; dc < 2; ++dc){
                bf16x8 kf = *(const bf16x8*)(Kl + (16 * fc + l16) * 64 +
                                             (((dc * 4 + lg) ^ (l16 & 7)) << 3));
                s[fc] = MFMA(qa[dc], kf, s[fc]);
            }
        }
        // scale + diagonal mask
        #pragma unroll
        for (int fc = 0; fc < 4; ++fc)
            #pragma unroll
            for (int r = 0; r < 4; ++r){
                float v = s[fc][r] * scale;
                if (qg0 + r == kb + fc * 16 + l16) v = -1e30f;
                s[fc][r] = v;
            }
        // online softmax: row max across the 16-lane group
        float mt[4];
        #pragma unroll
        for (int r = 0; r < 4; ++r){
            mt[r] = fmaxf(fmaxf(s[0][r], s[1][r]), fmaxf(s[2][r], s[3][r]));
            #pragma unroll
            for (int off = 1; off < 16; off <<= 1)
                mt[r] = fmaxf(mt[r], __shfl_xor(mt[r], off));
        }
        float al[4];
        #pragma unroll
        for (int r = 0; r < 4; ++r){
            float mn = fmaxf(mv[r], mt[r]);
            al[r] = __expf(mv[r] - mn);
            mv[r] = mn;
        }
        float rs[4] = {0.f, 0.f, 0.f, 0.f};
        #pragma unroll
        for (int fc = 0; fc < 4; ++fc)
            #pragma unroll
            for (int r = 0; r < 4; ++r){
                float p = __expf(s[fc][r] - mv[r]);
                rs[r] += p;
                Pl[wave][(lg * 4 + r) * 72 + fc * 16 + l16] = f2bf(p);
            }
        #pragma unroll
        for (int r = 0; r < 4; ++r){
            #pragma unroll
            for (int off = 1; off < 16; off <<= 1)
                rs[r] += __shfl_xor(rs[r], off);
            ls[r] = ls[r] * al[r] + rs[r];
        }
        #pragma unroll
        for (int dn = 0; dn < 4; ++dn)
            #pragma unroll
            for (int r = 0; r < 4; ++r) o[dn][r] *= al[r];
        // O += P V
        #pragma unroll
        for (int kc = 0; kc < 2; ++kc){
            bf16x8 pa = *(const bf16x8*)(&Pl[wave][l16 * 72 + kc * 32 + lg * 8]);
            #pragma unroll
            for (int dn = 0; dn < 4; ++dn){
                bf16x8 vf = *(const bf16x8*)(Vl + (16 * dn + l16) * 64 +
                                             (((kc * 4 + lg) ^ (l16 & 7)) << 3));
                o[dn] = MFMA(pa, vf, o[dn]);
            }
        }
    }
    // epilogue: normalize, store [b][n][h*64+d] bf16
    const int b = bh >> 3, h = bh & 7;
    #pragma unroll
    for (int r = 0; r < 4; ++r){
        float inv = 1.f / ls[r];
        int n = qg0 + r;
        size_t base = ((size_t)b * 4096 + n) * 512 + h * 64;
        #pragma unroll
        for (int dn = 0; dn < 4; ++dn)
            aout[base + dn * 16 + l16] = f2bf(o[dn][r] * inv);
    }
}

// ---------------- GEMM2: out = aout @ w_out^T + bias (fp32) ----------------
__global__ __launch_bounds__(256) void gemm_out_kernel(const u16* __restrict__ A, const u16* __restrict__ Bt,
                                                       const float* __restrict__ bias,
                                                       float* __restrict__ out){
    __shared__ u16 ldsA[128 * 64];
    __shared__ u16 ldsB[128 * 64];
    const f32x4 vzero = {0.f, 0.f, 0.f, 0.f};
    f32x4 acc[4][4];
    #pragma unroll
    for (int m = 0; m < 4; ++m)
        #pragma unroll
        for (int n = 0; n < 4; ++n) acc[m][n] = vzero;

    int brow = blockIdx.x * 128, bcol = blockIdx.y * 128;
    gemm_core(A, Bt, brow, bcol, ldsA, ldsB, acc);

    const int t = threadIdx.x, lane = t & 63, wave = t >> 6;
    const int l16 = lane & 15, lg = lane >> 4;
    const int wrow = (wave & 1) << 6, wcol = (wave >> 1) << 6;
    #pragma unroll
    for (int n = 0; n < 4; ++n){
        int e = bcol + wcol + 16 * n + l16;
        float bv = bias[e];
        #pragma unroll
        for (int m = 0; m < 4; ++m)
            #pragma unroll
            for (int r = 0; r < 4; ++r){
                int mg = brow + wrow + 16 * m + 4 * lg + r;
                out[(size_t)mg * 512 + e] = acc[m][n][r] + bv;
            }
    }
}

extern "C" void kernel_launch(void* const* d_in, const int* in_sizes, int n_in,
                              void* d_out, int out_size, void* d_ws, size_t ws_size,
                              hipStream_t stream){
    (void)in_sizes; (void)n_in; (void)out_size; (void)ws_size;
    const float* x     = (const float*)d_in[0];
    const float* w_qkv = (const float*)d_in[1];
    const float* w_out = (const float*)d_in[2];
    const float* b_out = (const float*)d_in[3];
    const float* temp  = (const float*)d_in[4];
    float* out = (float*)d_out;

    u16* ws   = (u16*)d_ws;
    u16* xbf  = ws;                              // 8192*512
    u16* wqt  = xbf + 8192 * 512;                // 1536*512
    u16* wot  = wqt + 1536 * 512;                // 512*512
    u16* qws  = wot + 512 * 512;                 // 16*4096*64
    u16* kws  = qws + 16 * 4096 * 64;
    u16* vtws = kws + 16 * 4096 * 64;
    u16* aout = xbf;                             // alias: xbf dead after GEMM1

    cvt_x_kernel<<<2048, 256, 0, stream>>>(x, xbf, 8192 * 512 / 8);
    tcvt_kernel<<<dim3(48, 16), 256, 0, stream>>>(w_qkv, wqt, 512, 1536);
    tcvt_kernel<<<dim3(16, 16), 256, 0, stream>>>(w_out, wot, 512, 512);
    gemm_qkv_kernel<<<dim3(64, 12), 256, 0, stream>>>(xbf, wqt, qws, kws, vtws);
    attn_kernel<<<1024, 256, 0, stream>>>(qws, kws, vtws, aout, temp);
    gemm_out_kernel<<<dim3(64, 4), 256, 0, stream>>>(aout, wot, b_out, out);
}

// Round 2
// 187.360 us; speedup vs baseline: 1.4272x; 1.4272x over previous
//
#include <hip/hip_runtime.h>

typedef __bf16 bf16x8 __attribute__((ext_vector_type(8)));
typedef float  f32x4  __attribute__((ext_vector_type(4)));
typedef unsigned short u16;
typedef unsigned int   u32;

#define MFMA(a,b,c) __builtin_amdgcn_mfma_f32_16x16x32_bf16((a),(b),(c),0,0,0)

__device__ __forceinline__ u16 f2bf(float f){
    u32 u = __builtin_bit_cast(u32, f);
    u += 0x7FFFu + ((u >> 16) & 1u);   // RNE
    return (u16)(u >> 16);
}

typedef __attribute__((address_space(3))) u32 lds32_t;
typedef __attribute__((address_space(1))) u32 glb32_t;

__device__ __forceinline__ void gll16(const u16* g, u16* l){
    __builtin_amdgcn_global_load_lds((const glb32_t*)g, (lds32_t*)l, 16, 0, 0);
}

// ---------------- convert kernels ----------------
__global__ __launch_bounds__(256) void cvt_x_kernel(const float* __restrict__ in,
                                                    u16* __restrict__ out, int n8){
    int i = blockIdx.x * 256 + threadIdx.x;
    if (i >= n8) return;
    const float4* p = (const float4*)in + (size_t)i * 2;
    float4 a = p[0], b = p[1];
    u16 r[8] = { f2bf(a.x), f2bf(a.y), f2bf(a.z), f2bf(a.w),
                 f2bf(b.x), f2bf(b.y), f2bf(b.z), f2bf(b.w) };
    *((uint4*)out + i) = *(const uint4*)r;
}

// in[R][C] fp32 -> out[C][R] bf16
__global__ __launch_bounds__(256) void tcvt_kernel(const float* __restrict__ in,
                                                   u16* __restrict__ out, int R, int C){
    __shared__ float tile[32][33];
    int c0 = blockIdx.x * 32, r0 = blockIdx.y * 32;
    int tx = threadIdx.x & 31, ty = threadIdx.x >> 5;   // ty 0..7
    #pragma unroll
    for (int i = 0; i < 32; i += 8)
        tile[ty + i][tx] = in[(size_t)(r0 + ty + i) * C + c0 + tx];
    __syncthreads();
    #pragma unroll
    for (int i = 0; i < 32; i += 8)
        out[(size_t)(c0 + ty + i) * R + r0 + tx] = f2bf(tile[tx][ty + i]);
}

// ---------------- shared GEMM mainloop ----------------
__device__ __forceinline__ void gemm_core(const u16* __restrict__ A, const u16* __restrict__ Bt,
                                          int brow, int bcol, u16* ldsA, u16* ldsB,
                                          f32x4 acc[4][4]){
    const int t = threadIdx.x;
    const int lane = t & 63, wave = t >> 6;
    const int l16 = lane & 15, lg = lane >> 4;
    const int wrow = (wave & 1) << 6, wcol = (wave >> 1) << 6;

    for (int ks = 0; ks < 8; ++ks){
        if (ks) __syncthreads();
        #pragma unroll
        for (int iss = 0; iss < 4; ++iss){
            int chunk = iss * 256 + t;
            int row = chunk >> 3, c = chunk & 7;
            int sw = (c ^ (row & 7)) << 3;
            gll16(A  + (size_t)(brow + row) * 512 + ks * 64 + sw,
                  ldsA + (size_t)(iss * 256 + wave * 64) * 8);
            gll16(Bt + (size_t)(bcol + row) * 512 + ks * 64 + sw,
                  ldsB + (size_t)(iss * 256 + wave * 64) * 8);
        }
        __syncthreads();
        #pragma unroll
        for (int kc = 0; kc < 2; ++kc){
            bf16x8 af[4], bfr[4];
            #pragma unroll
            for (int m = 0; m < 4; ++m){
                int r = wrow + 16 * m + l16;
                af[m] = *(const bf16x8*)(ldsA + r * 64 + (((kc * 4 + lg) ^ (l16 & 7)) << 3));
            }
            #pragma unroll
            for (int n = 0; n < 4; ++n){
                int r = wcol + 16 * n + l16;
                bfr[n] = *(const bf16x8*)(ldsB + r * 64 + (((kc * 4 + lg) ^ (l16 & 7)) << 3));
            }
            #pragma unroll
            for (int m = 0; m < 4; ++m)
                #pragma unroll
                for (int n = 0; n < 4; ++n)
                    acc[m][n] = MFMA(af[m], bfr[n], acc[m][n]);
        }
    }
}

// ---------------- GEMM1: qkv; q pre-scaled by exp(temp)*log2(e); v transposed ----------------
__global__ __launch_bounds__(256) void gemm_qkv_kernel(const u16* __restrict__ A, const u16* __restrict__ Bt,
                                                       u16* __restrict__ qws, u16* __restrict__ kws,
                                                       u16* __restrict__ vtws,
                                                       const float* __restrict__ temp){
    __shared__ u16 ldsA[128 * 64];
    __shared__ u16 ldsB[128 * 64];
    const f32x4 vzero = {0.f, 0.f, 0.f, 0.f};
    f32x4 acc[4][4];
    #pragma unroll
    for (int m = 0; m < 4; ++m)
        #pragma unroll
        for (int n = 0; n < 4; ++n) acc[m][n] = vzero;

    int brow = blockIdx.x * 128, bcol = blockIdx.y * 128;
    gemm_core(A, Bt, brow, bcol, ldsA, ldsB, acc);

    const int t = threadIdx.x, lane = t & 63, wave = t >> 6;
    const int l16 = lane & 15, lg = lane >> 4;
    const int wrow = (wave & 1) << 6, wcol = (wave >> 1) << 6;
    const int s = bcol >> 9;            // 0:q 1:k 2:v (uniform per block)

    if (s < 2){
        u16* dst = (s == 0) ? qws : kws;
        float qs = (s == 0) ? (__expf(temp[0]) * 1.44269504f) : 1.0f;
        #pragma unroll
        for (int n = 0; n < 4; ++n){
            int e = (bcol & 511) + wcol + 16 * n + l16;
            int h = e >> 6, d = e & 63;
            #pragma unroll
            for (int m = 0; m < 4; ++m)
                #pragma unroll
                for (int r = 0; r < 4; ++r){
                    int mg = brow + wrow + 16 * m + 4 * lg + r;
                    int b = mg >> 12, nn = mg & 4095;
                    dst[(((size_t)(b * 8 + h) * 4096 + nn) << 6) + d] = f2bf(acc[m][n][r] * qs);
                }
        }
    } else {
        #pragma unroll
        for (int n = 0; n < 4; ++n){
            int e = (bcol & 511) + wcol + 16 * n + l16;
            int h = e >> 6, d = e & 63;
            #pragma unroll
            for (int m = 0; m < 4; ++m)
                #pragma unroll
                for (int r = 0; r < 4; ++r){
                    int mg = brow + wrow + 16 * m + 4 * lg + r;
                    int b = mg >> 12, nn = mg & 4095;
                    vtws[((size_t)((b * 8 + h) * 64 + d) << 12) + nn] = f2bf(acc[m][n][r]);
                }
        }
    }
}

// ---------------- flash attention, swapped-operand (lane-local softmax rows) ----------------
__global__ __launch_bounds__(256) void attn_kernel(const u16* __restrict__ q, const u16* __restrict__ k,
                                                   const u16* __restrict__ vt, u16* __restrict__ aout){
    __shared__ u16 Kl[64 * 64];          // [kv][64] swizzled
    __shared__ u16 Vl[64 * 64];          // [d][kv] swizzled
    __shared__ u16 Pl[4][16 * 72];       // per-wave P tile [q][kv], padded rows
    const int bid = blockIdx.x;
    const int qt = bid & 63, bh = bid >> 6;
    const int t = threadIdx.x, lane = t & 63, wave = t >> 6;
    const int l16 = lane & 15, lg = lane >> 4;

    // lane-local q row (q already pre-scaled by exp(temp)*log2e)
    const int qrow = qt * 64 + wave * 16 + l16;
    const u16* qb = q + (((size_t)bh * 4096 + qrow) << 6);
    bf16x8 qa[2];
    qa[0] = *(const bf16x8*)(qb + (lg << 3));
    qa[1] = *(const bf16x8*)(qb + 32 + (lg << 3));

    const f32x4 vzero = {0.f, 0.f, 0.f, 0.f};
    f32x4 o[4];                                  // o[dn][r] = O[q=l16][d=16dn+4lg+r]
    #pragma unroll
    for (int i = 0; i < 4; ++i) o[i] = vzero;
    float mv = -INFINITY, ls = 0.f;              // state for row q=l16 (lane-local)

    for (int kb = 0; kb < 4096; kb += 64){
        __syncthreads();
        #pragma unroll
        for (int iss = 0; iss < 2; ++iss){
            int chunk = iss * 256 + t;
            int row = chunk >> 3, c = chunk & 7;
            int sw = (c ^ (row & 7)) << 3;
            gll16(k  + (((size_t)bh * 4096 + kb + row) << 6) + sw,
                  Kl + (iss * 256 + wave * 64) * 8);
            gll16(vt + ((size_t)(bh * 64 + row) << 12) + kb + sw,
                  Vl + (iss * 256 + wave * 64) * 8);
        }
        __syncthreads();

        // S^T = K Q^T : lane holds S[q=l16][kv=16fc+4lg+r]  (log2 domain)
        f32x4 s[4];
        #pragma unroll
        for (int fc = 0; fc < 4; ++fc){
            s[fc] = vzero;
            #pragma unroll
            for (int dc = 0; dc < 2; ++dc){
                bf16x8 kf = *(const bf16x8*)(Kl + (16 * fc + l16) * 64 +
                                             (((dc * 4 + lg) ^ (l16 & 7)) << 3));
                s[fc] = MFMA(kf, qa[dc], s[fc]);
            }
        }
        // diagonal mask: only in the tile containing this block's q range
        if (kb == qt * 64){
            int dd = wave * 16 + l16;            // kv offset of the diagonal for this lane
            #pragma unroll
            for (int fc = 0; fc < 4; ++fc)
                #pragma unroll
                for (int r = 0; r < 4; ++r)
                    if (dd == fc * 16 + 4 * lg + r) s[fc][r] = -1e30f;
        }
        // row max: in-lane tree + 2 cross-lane steps
        float pm0 = fmaxf(fmaxf(s[0][0], s[0][1]), fmaxf(s[0][2], s[0][3]));
        float pm1 = fmaxf(fmaxf(s[1][0], s[1][1]), fmaxf(s[1][2], s[1][3]));
        float pm2 = fmaxf(fmaxf(s[2][0], s[2][1]), fmaxf(s[2][2], s[2][3]));
        float pm3 = fmaxf(fmaxf(s[3][0], s[3][1]), fmaxf(s[3][2], s[3][3]));
        float pm = fmaxf(fmaxf(pm0, pm1), fmaxf(pm2, pm3));
        pm = fmaxf(pm, __shfl_xor(pm, 16));
        pm = fmaxf(pm, __shfl_xor(pm, 32));
        // defer-max: rescale only when the running max grew materially
        if (__any(pm > mv + 8.0f)){
            float mn = fmaxf(mv, pm);
            float al = __builtin_amdgcn_exp2f(mv - mn);
            mv = mn;
            ls *= al;
            #pragma unroll
            for (int dn = 0; dn < 4; ++dn)
                #pragma unroll
                for (int r = 0; r < 4; ++r) o[dn][r] *= al;
        }
        // P = exp2(S - m), truncated to bf16; ls summed from truncated values
        float rs0 = 0.f, rs1 = 0.f;
        #pragma unroll
        for (int fc = 0; fc < 4; ++fc){
            u32 pb[4];
            #pragma unroll
            for (int r = 0; r < 4; ++r){
                float p = __builtin_amdgcn_exp2f(s[fc][r] - mv);
                u32 bb = __builtin_bit_cast(u32, p) & 0xffff0000u;
                pb[r] = bb;
                if (r & 1) rs1 += __builtin_bit_cast(float, bb);
                else       rs0 += __builtin_bit_cast(float, bb);
            }
            uint2 w;
            w.x = __builtin_amdgcn_perm(pb[1], pb[0], 0x07060302u);
            w.y = __builtin_amdgcn_perm(pb[3], pb[2], 0x07060302u);
            *(uint2*)&Pl[wave][l16 * 72 + 16 * fc + 4 * lg] = w;
        }
        float rs = rs0 + rs1;
        rs += __shfl_xor(rs, 16);
        rs += __shfl_xor(rs, 32);
        ls += rs;
        // O^T += V^T P^T : same LDS reads, swapped operands
        #pragma unroll
        for (int kc = 0; kc < 2; ++kc){
            bf16x8 pa = *(const bf16x8*)(&Pl[wave][l16 * 72 + kc * 32 + lg * 8]);
            #pragma unroll
            for (int dn = 0; dn < 4; ++dn){
                bf16x8 vf = *(const bf16x8*)(Vl + (16 * dn + l16) * 64 +
                                             (((kc * 4 + lg) ^ (l16 & 7)) << 3));
                o[dn] = MFMA(vf, pa, o[dn]);
            }
        }
    }
    // epilogue: lane owns row q=l16; d = 16*dn + 4*lg + r (r contiguous -> b64 stores)
    const int b = bh >> 3, h = bh & 7;
    const float inv = __builtin_amdgcn_rcpf(ls);
    const int n = qt * 64 + wave * 16 + l16;
    size_t base = ((size_t)b * 4096 + n) * 512 + h * 64;
    #pragma unroll
    for (int dn = 0; dn < 4; ++dn){
        u16 e0 = f2bf(o[dn][0] * inv), e1 = f2bf(o[dn][1] * inv);
        u16 e2 = f2bf(o[dn][2] * inv), e3 = f2bf(o[dn][3] * inv);
        uint2 w;
        w.x = (u32)e0 | ((u32)e1 << 16);
        w.y = (u32)e2 | ((u32)e3 << 16);
        *(uint2*)&aout[base + dn * 16 + lg * 4] = w;
    }
}

// ---------------- GEMM2: out = aout @ w_out^T + bias (fp32) ----------------
__global__ __launch_bounds__(256) void gemm_out_kernel(const u16* __restrict__ A, const u16* __restrict__ Bt,
                                                       const float* __restrict__ bias,
                                                       float* __restrict__ out){
    __shared__ u16 ldsA[128 * 64];
    __shared__ u16 ldsB[128 * 64];
    const f32x4 vzero = {0.f, 0.f, 0.f, 0.f};
    f32x4 acc[4][4];
    #pragma unroll
    for (int m = 0; m < 4; ++m)
        #pragma unroll
        for (int n = 0; n < 4; ++n) acc[m][n] = vzero;

    int brow = blockIdx.x * 128, bcol = blockIdx.y * 128;
    gemm_core(A, Bt, brow, bcol, ldsA, ldsB, acc);

    const int t = threadIdx.x, lane = t & 63, wave = t >> 6;
    const int l16 = lane & 15, lg = lane >> 4;
    const int wrow = (wave & 1) << 6, wcol = (wave >> 1) << 6;
    #pragma unroll
    for (int n = 0; n < 4; ++n){
        int e = bcol + wcol + 16 * n + l16;
        float bv = bias[e];
        #pragma unroll
        for (int m = 0; m < 4; ++m)
            #pragma unroll
            for (int r = 0; r < 4; ++r){
                int mg = brow + wrow + 16 * m + 4 * lg + r;
                out[(size_t)mg * 512 + e] = acc[m][n][r] + bv;
            }
    }
}

extern "C" void kernel_launch(void* const* d_in, const int* in_sizes, int n_in,
                              void* d_out, int out_size, void* d_ws, size_t ws_size,
                              hipStream_t stream){
    (void)in_sizes; (void)n_in; (void)out_size; (void)ws_size;
    const float* x     = (const float*)d_in[0];
    const float* w_qkv = (const float*)d_in[1];
    const float* w_out = (const float*)d_in[2];
    const float* b_out = (const float*)d_in[3];
    const float* temp  = (const float*)d_in[4];
    float* out = (float*)d_out;

    u16* ws   = (u16*)d_ws;
    u16* xbf  = ws;                              // 8192*512
    u16* wqt  = xbf + 8192 * 512;                // 1536*512
    u16* wot  = wqt + 1536 * 512;                // 512*512
    u16* qws  = wot + 512 * 512;                 // 16*4096*64
    u16* kws  = qws + 16 * 4096 * 64;
    u16* vtws = kws + 16 * 4096 * 64;
    u16* aout = xbf;                             // alias: xbf dead after GEMM1

    cvt_x_kernel<<<2048, 256, 0, stream>>>(x, xbf, 8192 * 512 / 8);
    tcvt_kernel<<<dim3(48, 16), 256, 0, stream>>>(w_qkv, wqt, 512, 1536);
    tcvt_kernel<<<dim3(16, 16), 256, 0, stream>>>(w_out, wot, 512, 512);
    gemm_qkv_kernel<<<dim3(64, 12), 256, 0, stream>>>(xbf, wqt, qws, kws, vtws, temp);
    attn_kernel<<<1024, 256, 0, stream>>>(qws, kws, vtws, aout);
    gemm_out_kernel<<<dim3(64, 4), 256, 0, stream>>>(aout, wot, b_out, out);
}